// Round 2
// baseline (557.774 us; speedup 1.0000x reference)
//
#include <hip/hip_runtime.h>
#include <hip/hip_bf16.h>

#define SS 2048
#define HH 512

typedef __attribute__((ext_vector_type(8))) short short8;
typedef __attribute__((ext_vector_type(4))) float f32x4;

__device__ __forceinline__ float bflo(unsigned u) { return __uint_as_float(u << 16); }
__device__ __forceinline__ float bfhi(unsigned u) { return __uint_as_float(u & 0xffff0000u); }

__device__ __forceinline__ short f2bf(float v) {
  __hip_bfloat16 h = __float2bfloat16(v);
  return *reinterpret_cast<short*>(&h);
}

__device__ __forceinline__ float tanh_fast(float x) {
  x = fminf(fmaxf(x, -15.f), 15.f);
  float e = __expf(2.f * x);
  return 1.f - 2.f / (e + 1.f);
}

// ---------------- dtype detector: 1 = inputs are bf16, 0 = fp32 ----------------
__global__ void k_detect(const unsigned* __restrict__ Eu, int* __restrict__ flag) {
  int lane = threadIdx.x;  // 64 threads
  unsigned w = Eu[(size_t)lane * 4097];
  unsigned e = (w >> 7) & 0xFF;  // exponent field of the low bf16 half
  bool inr = (e >= 90 && e <= 140);
  unsigned long long m = __ballot(inr);
  if (lane == 0) *flag = (__popcll(m) >= 48) ? 1 : 0;
}

// ---------------- W1 transpose -> bf16 W1T[d][h] = W1[h][d] ----------------
__global__ __launch_bounds__(256) void k_transpose(const __hip_bfloat16* __restrict__ W1b,
                                                   const float* __restrict__ W1f,
                                                   const int* __restrict__ flagp,
                                                   __hip_bfloat16* __restrict__ W1T) {
  const int mode = *flagp;
  __shared__ __hip_bfloat16 t[64][65];
  int r0 = blockIdx.y * 64, c0 = blockIdx.x * 64;
  for (int i = threadIdx.x; i < 4096; i += 256) {
    int r = i >> 6, c = i & 63;
    size_t idx = (size_t)(r0 + r) * HH + c0 + c;
    float v = mode ? (float)W1b[idx] : W1f[idx];
    t[r][c] = __float2bfloat16(v);
  }
  __syncthreads();
  for (int i = threadIdx.x; i < 4096; i += 256) {
    int r = i >> 6, c = i & 63;
    W1T[(size_t)(c0 + r) * HH + r0 + c] = t[c][r];
  }
}

// ---------------- qp[b][d] = sum_h q[b][h] * W2[h][d] (fp32, atomics over h-chunks) ----
__global__ __launch_bounds__(256) void k_qp(const __hip_bfloat16* __restrict__ qb,
                                            const float* __restrict__ qf,
                                            const __hip_bfloat16* __restrict__ W2b,
                                            const float* __restrict__ W2f,
                                            const int* __restrict__ flagp,
                                            float* __restrict__ qp) {
  const int mode = *flagp;
  int b = blockIdx.x, h0 = blockIdx.y * 128;
  __shared__ float qs[128];
  if (threadIdx.x < 128) {
    size_t qi = (size_t)b * HH + h0 + threadIdx.x;
    qs[threadIdx.x] = mode ? (float)qb[qi] : qf[qi];
  }
  __syncthreads();
  int col = threadIdx.x * 2;
  float a0 = 0.f, a1 = 0.f;
  if (mode) {
#pragma unroll 4
    for (int i = 0; i < 128; ++i) {
      float qa = qs[i];
      unsigned u = *(const unsigned*)(W2b + (size_t)(h0 + i) * HH + col);
      a0 = fmaf(qa, bflo(u), a0);
      a1 = fmaf(qa, bfhi(u), a1);
    }
  } else {
#pragma unroll 4
    for (int i = 0; i < 128; ++i) {
      float qa = qs[i];
      float2 v = *(const float2*)(W2f + (size_t)(h0 + i) * HH + col);
      a0 = fmaf(qa, v.x, a0);
      a1 = fmaf(qa, v.y, a1);
    }
  }
  atomicAdd(&qp[b * HH + col], a0);
  atomicAdd(&qp[b * HH + col + 1], a1);
}

// ---------------- fused energy: e[b][s] = V . tanh(E[b][s]*W1 + qp[b]) ----------------
// 128-row M-tile/WG, 4 n-chunks of 128, BK=32, 16x16x32 bf16 MFMA.
// LDS chunk (row r, kgroup kg) at element r*32 + ((kg + (r>>1))&3)*8 (XOR swizzle).
__global__ __launch_bounds__(256) void k_energy(
    const __hip_bfloat16* __restrict__ Eb, const float* __restrict__ Ef,
    const __hip_bfloat16* __restrict__ W1T, const float* __restrict__ qp,
    const __hip_bfloat16* __restrict__ Vwb, const float* __restrict__ Vwf,
    const int* __restrict__ flagp, float* __restrict__ energy) {
  __shared__ __align__(16) __hip_bfloat16 At[128 * 32];
  __shared__ __align__(16) __hip_bfloat16 Bt[128 * 32];
  __shared__ float qps[HH];
  __shared__ float Vs[HH];

  const int mode = *flagp;
  const int tid = threadIdx.x;
  const int wave = tid >> 6, lane = tid & 63;
  const int quad = lane >> 4, l16 = lane & 15;
  const int row0 = blockIdx.x * 128;  // global row in [0, B*S); tiles never straddle b
  const int b = row0 >> 11;

  for (int i = tid; i < HH; i += 256) {
    qps[i] = qp[b * HH + i];
    Vs[i] = mode ? (float)Vwb[i] : Vwf[i];
  }

  // staging lane mapping: lane -> (row = lane>>2, slot = lane&3) within wave's 16-row group
  const int rs0 = wave * 32 + (lane >> 2);
  const int rs1 = rs0 + 16;
  const int kg0 = ((lane & 3) - (rs0 >> 1)) & 3;
  const int kg1 = ((lane & 3) - (rs1 >> 1)) & 3;

  const size_t eBase = (size_t)row0 * HH;
  const int aoff0 = rs0 * HH + kg0 * 8;
  const int aoff1 = rs1 * HH + kg1 * 8;

  __hip_bfloat16* aW0 = At + (wave * 2 + 0) * 512 + lane * 8;
  __hip_bfloat16* aW1 = At + (wave * 2 + 1) * 512 + lane * 8;
  __hip_bfloat16* bW0 = Bt + (wave * 2 + 0) * 512 + lane * 8;
  __hip_bfloat16* bW1 = Bt + (wave * 2 + 1) * 512 + lane * 8;

  // fragment read offsets: A[m=l16][k=quad*8+j], B[k=quad*8+j][n=l16] (Bt rows = n)
  const int rf0 = wave * 32 + l16;
  const int rf1 = rf0 + 16;
  const int offA0 = rf0 * 32 + (((quad + (rf0 >> 1)) & 3) << 3);
  const int offA1 = rf1 * 32 + (((quad + (rf1 >> 1)) & 3) << 3);
  int offB[8];
#pragma unroll
  for (int cb = 0; cb < 8; ++cb) {
    int n = cb * 16 + l16;
    offB[cb] = n * 32 + (((quad + (n >> 1)) & 3) << 3);
  }

  float eacc[2][4] = {{0.f, 0.f, 0.f, 0.f}, {0.f, 0.f, 0.f, 0.f}};

  for (int nc = 0; nc < 4; ++nc) {
    const int boff0 = (nc * 128 + rs0) * HH + kg0 * 8;
    const int boff1 = (nc * 128 + rs1) * HH + kg1 * 8;

    f32x4 acc[2][8];
#pragma unroll
    for (int rb = 0; rb < 2; ++rb)
#pragma unroll
      for (int cb = 0; cb < 8; ++cb) acc[rb][cb] = (f32x4){0.f, 0.f, 0.f, 0.f};

    for (int kt = 0; kt < 16; ++kt) {
      const int ko = kt * 32;
      __syncthreads();  // protect LDS from previous iteration's readers
      short8 vb0 = *(const short8*)(W1T + boff0 + ko);
      short8 vb1 = *(const short8*)(W1T + boff1 + ko);
      short8 va0, va1;
      if (mode) {
        va0 = *(const short8*)(Eb + eBase + aoff0 + ko);
        va1 = *(const short8*)(Eb + eBase + aoff1 + ko);
      } else {
        const float* p0 = Ef + eBase + aoff0 + ko;
        const float* p1 = Ef + eBase + aoff1 + ko;
        f32x4 x0 = *(const f32x4*)p0, x1 = *(const f32x4*)(p0 + 4);
        f32x4 y0 = *(const f32x4*)p1, y1 = *(const f32x4*)(p1 + 4);
#pragma unroll
        for (int j = 0; j < 4; ++j) {
          va0[j] = f2bf(x0[j]);
          va0[j + 4] = f2bf(x1[j]);
          va1[j] = f2bf(y0[j]);
          va1[j + 4] = f2bf(y1[j]);
        }
      }
      *(short8*)aW0 = va0;
      *(short8*)aW1 = va1;
      *(short8*)bW0 = vb0;
      *(short8*)bW1 = vb1;
      __syncthreads();

      short8 af0 = *(const short8*)(At + offA0);
      short8 af1 = *(const short8*)(At + offA1);
#pragma unroll
      for (int cb = 0; cb < 8; ++cb) {
        short8 bf = *(const short8*)(Bt + offB[cb]);
        acc[0][cb] = __builtin_amdgcn_mfma_f32_16x16x32_bf16(af0, bf, acc[0][cb], 0, 0, 0);
        acc[1][cb] = __builtin_amdgcn_mfma_f32_16x16x32_bf16(af1, bf, acc[1][cb], 0, 0, 0);
      }
    }

    // epilogue: +qp, tanh, dot with V   (C/D: col=l16, row=quad*4+r)
#pragma unroll
    for (int rb = 0; rb < 2; ++rb)
#pragma unroll
      for (int cb = 0; cb < 8; ++cb) {
        int col = nc * 128 + cb * 16 + l16;
        float qv = qps[col], vv = Vs[col];
#pragma unroll
        for (int r = 0; r < 4; ++r) {
          float t = tanh_fast(acc[rb][cb][r] + qv);
          eacc[rb][r] = fmaf(vv, t, eacc[rb][r]);
        }
      }
  }

  // sum over the 16 column-groups held across l16 lanes, then write
#pragma unroll
  for (int rb = 0; rb < 2; ++rb)
#pragma unroll
    for (int r = 0; r < 4; ++r) {
      float v = eacc[rb][r];
#pragma unroll
      for (int o = 1; o < 16; o <<= 1) v += __shfl_xor(v, o);
      if (l16 == 0) energy[row0 + wave * 32 + rb * 16 + quad * 4 + r] = v;
    }
}

// ---------------- masked softmax stats per batch ----------------
__global__ __launch_bounds__(256) void k_stats(const float* __restrict__ energy,
                                               const int* __restrict__ lens,
                                               float* __restrict__ stats) {
  int b = blockIdx.x, tid = threadIdx.x;
  int len = lens[b];
  const float* eb = energy + b * SS;
  float m = -3.0e38f;
  for (int s = tid; s < len; s += 256) m = fmaxf(m, eb[s]);
#pragma unroll
  for (int o = 1; o < 64; o <<= 1) m = fmaxf(m, __shfl_xor(m, o));
  __shared__ float sm[4];
  __shared__ float sd[4];
  int wv = tid >> 6;
  if ((tid & 63) == 0) sm[wv] = m;
  __syncthreads();
  m = fmaxf(fmaxf(sm[0], sm[1]), fmaxf(sm[2], sm[3]));
  float ssum = 0.f;
  for (int s = tid; s < len; s += 256) ssum += __expf(eb[s] - m);
#pragma unroll
  for (int o = 1; o < 64; o <<= 1) ssum += __shfl_xor(ssum, o);
  if ((tid & 63) == 0) sd[wv] = ssum;
  __syncthreads();
  if (tid == 0) {
    stats[b * 2] = m;
    stats[b * 2 + 1] = sd[0] + sd[1] + sd[2] + sd[3];
  }
}

// ---------------- context partials ----------------
__global__ __launch_bounds__(256) void k_ctx(const __hip_bfloat16* __restrict__ Eb,
                                             const float* __restrict__ Ef,
                                             const float* __restrict__ energy,
                                             const float* __restrict__ stats,
                                             const int* __restrict__ lens,
                                             const int* __restrict__ flagp,
                                             float* __restrict__ ctx) {
  const int mode = *flagp;
  int bc = blockIdx.x;
  int b = bc >> 3, c = bc & 7;
  int len = lens[b];
  int s0 = c * 256;
  if (s0 >= len) return;  // block-uniform
  int tid = threadIdx.x;
  __shared__ float p[256];
  float m = stats[b * 2];
  float inv = 1.f / stats[b * 2 + 1];
  int s = s0 + tid;
  p[tid] = (s < len) ? __expf(energy[b * SS + s] - m) * inv : 0.f;
  __syncthreads();
  int n = min(256, len - s0);
  int h0 = tid * 2;
  float a0 = 0.f, a1 = 0.f;
  if (mode) {
    const unsigned* base = (const unsigned*)(Eb + ((size_t)(b * SS + s0) * HH + h0));
    for (int i = 0; i < n; ++i) {
      float w = p[i];
      unsigned u = base[(size_t)i * 256];  // 256 dwords per 512-bf16 row
      a0 = fmaf(w, bflo(u), a0);
      a1 = fmaf(w, bfhi(u), a1);
    }
  } else {
    const float2* base = (const float2*)(Ef + ((size_t)(b * SS + s0) * HH + h0));
    for (int i = 0; i < n; ++i) {
      float w = p[i];
      float2 v = base[(size_t)i * 256];  // 256 float2 per 512-f32 row
      a0 = fmaf(w, v.x, a0);
      a1 = fmaf(w, v.y, a1);
    }
  }
  atomicAdd(&ctx[b * HH + h0], a0);
  atomicAdd(&ctx[b * HH + h0 + 1], a1);
}

// ---------------- store (dtype per flag) ----------------
__global__ __launch_bounds__(256) void k_store(const float* __restrict__ ctx,
                                               const int* __restrict__ flagp,
                                               __hip_bfloat16* __restrict__ outb,
                                               float* __restrict__ outf) {
  const int mode = *flagp;
  int i = blockIdx.x * 256 + threadIdx.x;
  if (mode)
    outb[i] = __float2bfloat16(ctx[i]);
  else
    outf[i] = ctx[i];
}

extern "C" void kernel_launch(void* const* d_in, const int* in_sizes, int n_in,
                              void* d_out, int out_size, void* d_ws, size_t ws_size,
                              hipStream_t stream) {
  const __hip_bfloat16* qb  = (const __hip_bfloat16*)d_in[0];
  const float*          qf  = (const float*)d_in[0];
  const __hip_bfloat16* Eb  = (const __hip_bfloat16*)d_in[1];
  const float*          Ef  = (const float*)d_in[1];
  const int* lens           = (const int*)d_in[2];
  const __hip_bfloat16* W1b = (const __hip_bfloat16*)d_in[3];
  const float*          W1f = (const float*)d_in[3];
  const __hip_bfloat16* W2b = (const __hip_bfloat16*)d_in[4];
  const float*          W2f = (const float*)d_in[4];
  const __hip_bfloat16* Vwb = (const __hip_bfloat16*)d_in[5];
  const float*          Vwf = (const float*)d_in[5];
  __hip_bfloat16* outb      = (__hip_bfloat16*)d_out;
  float*          outf      = (float*)d_out;

  char* ws = (char*)d_ws;
  float* energy       = (float*)(ws);                    // 512 KB
  __hip_bfloat16* W1T = (__hip_bfloat16*)(ws + 524288);  // 512 KB
  float* qp           = (float*)(ws + 1048576);          // 128 KB
  float* ctx          = (float*)(ws + 1179648);          // 128 KB
  float* stats        = (float*)(ws + 1310720);          // 512 B
  int* flag           = (int*)(ws + 1311232);            // 4 B

  hipMemsetAsync(ws + 1048576, 0, 262656, stream);  // zero qp + ctx + stats

  k_detect<<<dim3(1), 64, 0, stream>>>((const unsigned*)d_in[1], flag);
  k_transpose<<<dim3(8, 8), 256, 0, stream>>>(W1b, W1f, flag, W1T);
  k_qp<<<dim3(64, 4), 256, 0, stream>>>(qb, qf, W2b, W2f, flag, qp);
  k_energy<<<dim3(1024), 256, 0, stream>>>(Eb, Ef, W1T, qp, Vwb, Vwf, flag, energy);
  k_stats<<<dim3(64), 256, 0, stream>>>(energy, lens, stats);
  k_ctx<<<dim3(512), 256, 0, stream>>>(Eb, Ef, energy, stats, lens, flag, ctx);
  k_store<<<dim3(128), 256, 0, stream>>>(ctx, flag, outb, outf);
}

// Round 3
// 484.866 us; speedup vs baseline: 1.1504x; 1.1504x over previous
//
#include <hip/hip_runtime.h>
#include <hip/hip_bf16.h>

#define SS 2048
#define HH 512

typedef __attribute__((ext_vector_type(8))) short short8;
typedef __attribute__((ext_vector_type(4))) float f32x4;

__device__ __forceinline__ float bflo(unsigned u) { return __uint_as_float(u << 16); }
__device__ __forceinline__ float bfhi(unsigned u) { return __uint_as_float(u & 0xffff0000u); }

__device__ __forceinline__ short f2bf(float v) {
  __hip_bfloat16 h = __float2bfloat16(v);
  return *reinterpret_cast<short*>(&h);
}

__device__ __forceinline__ float tanh_fast(float x) {
  x = fminf(fmaxf(x, -15.f), 15.f);
  float e = __expf(2.f * x);
  return 1.f - 2.f / (e + 1.f);
}

// ---------------- dtype detector: 1 = inputs are bf16, 0 = fp32 ----------------
__global__ void k_detect(const unsigned* __restrict__ Eu, int* __restrict__ flag) {
  int lane = threadIdx.x;  // 64 threads
  unsigned w = Eu[(size_t)lane * 4097];
  unsigned e = (w >> 7) & 0xFF;  // exponent field of the low bf16 half
  bool inr = (e >= 90 && e <= 140);
  unsigned long long m = __ballot(inr);
  if (lane == 0) *flag = (__popcll(m) >= 48) ? 1 : 0;
}

// ---------------- W1 transpose -> bf16 W1T[d][h] = W1[h][d] ----------------
__global__ __launch_bounds__(256) void k_transpose(const __hip_bfloat16* __restrict__ W1b,
                                                   const float* __restrict__ W1f,
                                                   const int* __restrict__ flagp,
                                                   __hip_bfloat16* __restrict__ W1T) {
  const int mode = *flagp;
  __shared__ __hip_bfloat16 t[64][65];
  int r0 = blockIdx.y * 64, c0 = blockIdx.x * 64;
  for (int i = threadIdx.x; i < 4096; i += 256) {
    int r = i >> 6, c = i & 63;
    size_t idx = (size_t)(r0 + r) * HH + c0 + c;
    float v = mode ? (float)W1b[idx] : W1f[idx];
    t[r][c] = __float2bfloat16(v);
  }
  __syncthreads();
  for (int i = threadIdx.x; i < 4096; i += 256) {
    int r = i >> 6, c = i & 63;
    W1T[(size_t)(c0 + r) * HH + r0 + c] = t[c][r];
  }
}

// ---------------- qp[b][d] = sum_h q[b][h] * W2[h][d] ----------------
__global__ __launch_bounds__(256) void k_qp(const __hip_bfloat16* __restrict__ qb,
                                            const float* __restrict__ qf,
                                            const __hip_bfloat16* __restrict__ W2b,
                                            const float* __restrict__ W2f,
                                            const int* __restrict__ flagp,
                                            float* __restrict__ qp) {
  const int mode = *flagp;
  int b = blockIdx.x, h0 = blockIdx.y * 128;
  __shared__ float qs[128];
  if (threadIdx.x < 128) {
    size_t qi = (size_t)b * HH + h0 + threadIdx.x;
    qs[threadIdx.x] = mode ? (float)qb[qi] : qf[qi];
  }
  __syncthreads();
  int col = threadIdx.x * 2;
  float a0 = 0.f, a1 = 0.f;
  if (mode) {
#pragma unroll 4
    for (int i = 0; i < 128; ++i) {
      float qa = qs[i];
      unsigned u = *(const unsigned*)(W2b + (size_t)(h0 + i) * HH + col);
      a0 = fmaf(qa, bflo(u), a0);
      a1 = fmaf(qa, bfhi(u), a1);
    }
  } else {
#pragma unroll 4
    for (int i = 0; i < 128; ++i) {
      float qa = qs[i];
      float2 v = *(const float2*)(W2f + (size_t)(h0 + i) * HH + col);
      a0 = fmaf(qa, v.x, a0);
      a1 = fmaf(qa, v.y, a1);
    }
  }
  atomicAdd(&qp[b * HH + col], a0);
  atomicAdd(&qp[b * HH + col + 1], a1);
}

// ---------------- fused energy: e[b][s] = V . tanh(E[b][s]*W1 + qp[b]) ----------------
// 128-row M-tile/WG; A frags resident in regs (short8 afr[2][16] = 128 VGPRs);
// B streamed via 8 KB LDS, register-prefetched one K-step ahead.
// LDS B chunk (n, kg) at element n*32 + ((kg + (n>>1))&3)*8 (XOR swizzle, 0 conflicts).
__global__ __launch_bounds__(256, 2) void k_energy(
    const __hip_bfloat16* __restrict__ Eb, const float* __restrict__ Ef,
    const __hip_bfloat16* __restrict__ W1T, const float* __restrict__ qp,
    const __hip_bfloat16* __restrict__ Vwb, const float* __restrict__ Vwf,
    const int* __restrict__ flagp, const int* __restrict__ lens,
    float* __restrict__ energy) {
  __shared__ __align__(16) __hip_bfloat16 Bt[128 * 32];  // 8 KB
  __shared__ float qps[HH];
  __shared__ float Vs[HH];

  const int tid = threadIdx.x;
  const int wave = tid >> 6, lane = tid & 63;
  const int quad = lane >> 4, l16 = lane & 15;
  const int row0 = blockIdx.x * 128;  // tiles never straddle a batch
  const int b = row0 >> 11;
  if ((row0 & 2047) >= lens[b]) return;  // fully-masked tile: consumers ignore s>=len

  const int mode = *flagp;

  for (int i = tid; i < HH; i += 256) {
    qps[i] = qp[b * HH + i];
    Vs[i] = mode ? (float)Vwb[i] : Vwf[i];
  }

  // ---- A fragments -> registers (E read exactly once) ----
  // afr[rb][kt]: A[m = wave*32 + rb*16 + l16][k = kt*32 + quad*8 + j]
  short8 afr[2][16];
  {
    const size_t eBase = (size_t)row0 * HH + (size_t)(wave * 32 + l16) * HH + quad * 8;
    if (mode) {
      const __hip_bfloat16* pa = Eb + eBase;
#pragma unroll
      for (int kt = 0; kt < 16; ++kt) {
        afr[0][kt] = *(const short8*)(pa + kt * 32);
        afr[1][kt] = *(const short8*)(pa + 16 * HH + kt * 32);
      }
    } else {
      const float* pa = Ef + eBase;
#pragma unroll
      for (int kt = 0; kt < 16; ++kt) {
#pragma unroll
        for (int rb = 0; rb < 2; ++rb) {
          const float* p = pa + rb * 16 * HH + kt * 32;
          f32x4 x0 = *(const f32x4*)p;
          f32x4 x1 = *(const f32x4*)(p + 4);
          short8 v;
#pragma unroll
          for (int j = 0; j < 4; ++j) {
            v[j] = f2bf(x0[j]);
            v[j + 4] = f2bf(x1[j]);
          }
          afr[rb][kt] = v;
        }
      }
    }
  }

  // ---- B staging lane mapping (16B chunk (n, kg) per lane, swizzled slot = lane*16B) ----
  const int rs0 = wave * 32 + (lane >> 2);
  const int rs1 = rs0 + 16;
  const int kg0 = ((lane & 3) - (rs0 >> 1)) & 3;
  const int kg1 = ((lane & 3) - (rs1 >> 1)) & 3;
  const __hip_bfloat16* pb0 = W1T + (size_t)rs0 * HH + kg0 * 8;
  const __hip_bfloat16* pb1 = W1T + (size_t)rs1 * HH + kg1 * 8;
  __hip_bfloat16* bW0 = Bt + wave * 1024 + lane * 8;
  __hip_bfloat16* bW1 = bW0 + 512;

  // fragment read offsets: B[k=quad*8+j][n = cb*16 + l16]
  int offB[8];
#pragma unroll
  for (int cb = 0; cb < 8; ++cb) {
    int n = cb * 16 + l16;
    offB[cb] = n * 32 + (((quad + (n >> 1)) & 3) << 3);
  }

  // prefetch B step 0
  short8 bp0 = *(const short8*)(pb0);
  short8 bp1 = *(const short8*)(pb1);

  float eacc[2][4] = {{0.f, 0.f, 0.f, 0.f}, {0.f, 0.f, 0.f, 0.f}};

  for (int nc = 0; nc < 4; ++nc) {
    f32x4 acc[2][8];
#pragma unroll
    for (int rb = 0; rb < 2; ++rb)
#pragma unroll
      for (int cb = 0; cb < 8; ++cb) acc[rb][cb] = (f32x4){0.f, 0.f, 0.f, 0.f};

#pragma unroll
    for (int kt = 0; kt < 16; ++kt) {
      __syncthreads();  // previous readers done with Bt
      *(short8*)bW0 = bp0;
      *(short8*)bW1 = bp1;
      int t = nc * 16 + kt + 1;
      if (t > 63) t = 63;                          // redundant re-read on last step
      int o = ((t >> 4) << 16) + ((t & 15) << 5);  // (t>>4)*128*512 + (t&15)*32
      bp0 = *(const short8*)(pb0 + o);             // prefetch next chunk (L2-resident)
      bp1 = *(const short8*)(pb1 + o);
      __syncthreads();  // Bt ready

      short8 af0 = afr[0][kt];
      short8 af1 = afr[1][kt];
#pragma unroll
      for (int cb = 0; cb < 8; ++cb) {
        short8 bf = *(const short8*)(Bt + offB[cb]);
        acc[0][cb] = __builtin_amdgcn_mfma_f32_16x16x32_bf16(af0, bf, acc[0][cb], 0, 0, 0);
        acc[1][cb] = __builtin_amdgcn_mfma_f32_16x16x32_bf16(af1, bf, acc[1][cb], 0, 0, 0);
      }
    }

    // epilogue: +qp, tanh, dot with V   (C/D: col=l16, row=quad*4+r)
#pragma unroll
    for (int rb = 0; rb < 2; ++rb)
#pragma unroll
      for (int cb = 0; cb < 8; ++cb) {
        int col = nc * 128 + cb * 16 + l16;
        float qv = qps[col], vv = Vs[col];
#pragma unroll
        for (int r = 0; r < 4; ++r) {
          float t = tanh_fast(acc[rb][cb][r] + qv);
          eacc[rb][r] = fmaf(vv, t, eacc[rb][r]);
        }
      }
  }

  // sum over the 16 column-groups held across l16 lanes, then write
#pragma unroll
  for (int rb = 0; rb < 2; ++rb)
#pragma unroll
    for (int r = 0; r < 4; ++r) {
      float v = eacc[rb][r];
#pragma unroll
      for (int o = 1; o < 16; o <<= 1) v += __shfl_xor(v, o);
      if (l16 == 0) energy[row0 + wave * 32 + rb * 16 + quad * 4 + r] = v;
    }
}

// ---------------- masked softmax stats per batch ----------------
__global__ __launch_bounds__(256) void k_stats(const float* __restrict__ energy,
                                               const int* __restrict__ lens,
                                               float* __restrict__ stats) {
  int b = blockIdx.x, tid = threadIdx.x;
  int len = lens[b];
  const float* eb = energy + b * SS;
  float m = -3.0e38f;
  for (int s = tid; s < len; s += 256) m = fmaxf(m, eb[s]);
#pragma unroll
  for (int o = 1; o < 64; o <<= 1) m = fmaxf(m, __shfl_xor(m, o));
  __shared__ float sm[4];
  __shared__ float sd[4];
  int wv = tid >> 6;
  if ((tid & 63) == 0) sm[wv] = m;
  __syncthreads();
  m = fmaxf(fmaxf(sm[0], sm[1]), fmaxf(sm[2], sm[3]));
  float ssum = 0.f;
  for (int s = tid; s < len; s += 256) ssum += __expf(eb[s] - m);
#pragma unroll
  for (int o = 1; o < 64; o <<= 1) ssum += __shfl_xor(ssum, o);
  if ((tid & 63) == 0) sd[wv] = ssum;
  __syncthreads();
  if (tid == 0) {
    stats[b * 2] = m;
    stats[b * 2 + 1] = sd[0] + sd[1] + sd[2] + sd[3];
  }
}

// ---------------- context partials: 16 s-chunks of 128 rows per batch ----------------
__global__ __launch_bounds__(256) void k_ctx(const __hip_bfloat16* __restrict__ Eb,
                                             const float* __restrict__ Ef,
                                             const float* __restrict__ energy,
                                             const float* __restrict__ stats,
                                             const int* __restrict__ lens,
                                             const int* __restrict__ flagp,
                                             float* __restrict__ ctx) {
  const int mode = *flagp;
  int bc = blockIdx.x;
  int b = bc >> 4, c = bc & 15;
  int len = lens[b];
  int s0 = c * 128;
  if (s0 >= len) return;  // block-uniform
  int tid = threadIdx.x;
  __shared__ float p[128];
  __shared__ f32x4 part[128];
  float m = stats[b * 2];
  float inv = 1.f / stats[b * 2 + 1];
  if (tid < 128) {
    int s = s0 + tid;
    p[tid] = (s < len) ? __expf(energy[b * SS + s] - m) * inv : 0.f;
  }
  __syncthreads();
  int n = min(128, len - s0);
  int h0 = (tid & 127) * 4;
  int r = tid >> 7;  // 0/1: waves {0,1} take even rows, {2,3} odd
  f32x4 a = {0.f, 0.f, 0.f, 0.f};
  if (mode) {
    const __hip_bfloat16* base = Eb + (size_t)(b * SS + s0) * HH + h0;
#pragma unroll 2
    for (int i = r; i < n; i += 2) {
      float w = p[i];
      uint2 u = *(const uint2*)(base + (size_t)i * HH);
      a[0] = fmaf(w, bflo(u.x), a[0]);
      a[1] = fmaf(w, bfhi(u.x), a[1]);
      a[2] = fmaf(w, bflo(u.y), a[2]);
      a[3] = fmaf(w, bfhi(u.y), a[3]);
    }
  } else {
    const float* base = Ef + (size_t)(b * SS + s0) * HH + h0;
#pragma unroll 2
    for (int i = r; i < n; i += 2) {
      float w = p[i];
      f32x4 v = *(const f32x4*)(base + (size_t)i * HH);
      a[0] = fmaf(w, v[0], a[0]);
      a[1] = fmaf(w, v[1], a[1]);
      a[2] = fmaf(w, v[2], a[2]);
      a[3] = fmaf(w, v[3], a[3]);
    }
  }
  if (tid >= 128) part[tid - 128] = a;
  __syncthreads();
  if (tid < 128) {
    f32x4 o = part[tid];
    atomicAdd(&ctx[b * HH + h0 + 0], a[0] + o[0]);
    atomicAdd(&ctx[b * HH + h0 + 1], a[1] + o[1]);
    atomicAdd(&ctx[b * HH + h0 + 2], a[2] + o[2]);
    atomicAdd(&ctx[b * HH + h0 + 3], a[3] + o[3]);
  }
}

// ---------------- store (dtype per flag) ----------------
__global__ __launch_bounds__(256) void k_store(const float* __restrict__ ctx,
                                               const int* __restrict__ flagp,
                                               __hip_bfloat16* __restrict__ outb,
                                               float* __restrict__ outf) {
  const int mode = *flagp;
  int i = blockIdx.x * 256 + threadIdx.x;
  if (mode)
    outb[i] = __float2bfloat16(ctx[i]);
  else
    outf[i] = ctx[i];
}

extern "C" void kernel_launch(void* const* d_in, const int* in_sizes, int n_in,
                              void* d_out, int out_size, void* d_ws, size_t ws_size,
                              hipStream_t stream) {
  const __hip_bfloat16* qb  = (const __hip_bfloat16*)d_in[0];
  const float*          qf  = (const float*)d_in[0];
  const __hip_bfloat16* Eb  = (const __hip_bfloat16*)d_in[1];
  const float*          Ef  = (const float*)d_in[1];
  const int* lens           = (const int*)d_in[2];
  const __hip_bfloat16* W1b = (const __hip_bfloat16*)d_in[3];
  const float*          W1f = (const float*)d_in[3];
  const __hip_bfloat16* W2b = (const __hip_bfloat16*)d_in[4];
  const float*          W2f = (const float*)d_in[4];
  const __hip_bfloat16* Vwb = (const __hip_bfloat16*)d_in[5];
  const float*          Vwf = (const float*)d_in[5];
  __hip_bfloat16* outb      = (__hip_bfloat16*)d_out;
  float*          outf      = (float*)d_out;

  char* ws = (char*)d_ws;
  float* energy       = (float*)(ws);                    // 512 KB
  __hip_bfloat16* W1T = (__hip_bfloat16*)(ws + 524288);  // 512 KB
  float* qp           = (float*)(ws + 1048576);          // 128 KB
  float* ctx          = (float*)(ws + 1179648);          // 128 KB
  float* stats        = (float*)(ws + 1310720);          // 512 B
  int* flag           = (int*)(ws + 1311232);            // 4 B

  hipMemsetAsync(ws + 1048576, 0, 262656, stream);  // zero qp + ctx + stats

  k_detect<<<dim3(1), 64, 0, stream>>>((const unsigned*)d_in[1], flag);
  k_transpose<<<dim3(8, 8), 256, 0, stream>>>(W1b, W1f, flag, W1T);
  k_qp<<<dim3(64, 4), 256, 0, stream>>>(qb, qf, W2b, W2f, flag, qp);
  k_energy<<<dim3(1024), 256, 0, stream>>>(Eb, Ef, W1T, qp, Vwb, Vwf, flag, lens, energy);
  k_stats<<<dim3(64), 256, 0, stream>>>(energy, lens, stats);
  k_ctx<<<dim3(1024), 256, 0, stream>>>(Eb, Ef, energy, stats, lens, flag, ctx);
  k_store<<<dim3(128), 256, 0, stream>>>(ctx, flag, outb, outf);
}